// Round 3
// baseline (388.756 us; speedup 1.0000x reference)
//
#include <hip/hip_runtime.h>

// Circuit scan: states[r] <- a + b - 2ab over 64 steps, operands gathered
// from concat(sigmoid(4*clip(P[:,b,t])), states) by fixed indices wa/wb.
//
// Decomposition: 1 block = 1 wave = 1 batch element. Zero barriers:
// same-wave LDS ops execute in program order (DS pipe is per-wave FIFO),
// so the write->read dependency across scan steps needs no sync.
#define N_IN   256
#define N_REG  256
#define NBATCH 4096
#define TT     64
#define TC     16              // timesteps staged per chunk (64B/row = 1 sector)
#define NCHUNK (TT / TC)
#define XT_LD  17              // odd stride: random-row gathers hit all 32 banks
#define ST_BASE (N_IN * XT_LD) // state array base (words)

__global__ __launch_bounds__(64, 2) void circuit_scan(
    const float* __restrict__ P,
    const int*   __restrict__ wa,
    const int*   __restrict__ wb,
    float*       __restrict__ out)
{
    // lds[0 .. ST_BASE)            xt[r][t] = sigmoid(4*clip(P[r][b][c*16+t]))
    // lds[ST_BASE .. ST_BASE+256)  states
    __shared__ float lds[ST_BASE + N_REG];   // 18,432 B -> 8 blocks/CU

    const int lane = threadIdx.x;            // 0..63
    const int b    = blockIdx.x;
    const float* Pb = P + (size_t)b * TT;

    // Per-lane operand setup: lane owns registers r = lane + 64k, k=0..3.
    const float* pa0[4]; const float* pb0[4];
    int inca[4], incb[4];
    float sv[4];

    #pragma unroll
    for (int k = 0; k < 4; ++k) {
        const int r  = lane + 64 * k;
        const int ia = wa[r];
        const int ib = wb[r];
        const bool axk = ia < N_IN;
        const bool bxk = ib < N_IN;
        // X-type operand: walks xt[ia][t], +1 word per step (reset per chunk).
        // State-type operand: fixed address in the state region.
        pa0[k] = lds + (axk ? ia * XT_LD : ST_BASE + (ia - N_IN));
        pb0[k] = lds + (bxk ? ib * XT_LD : ST_BASE + (ib - N_IN));
        inca[k] = axk ? 1 : 0;
        incb[k] = bxk ? 1 : 0;
        lds[ST_BASE + r] = 0.5f;             // init states (own wave only)
        sv[k] = 0.5f;
    }

    // Prefetch chunk 0: 4 rows/lane x 16 floats = 16 float4 (64 B/row = 1 sector)
    float4 pf[16];
    #pragma unroll
    for (int k2 = 0; k2 < 4; ++k2) {
        const size_t rbase = (size_t)(lane + 64 * k2) * ((size_t)NBATCH * TT);
        #pragma unroll
        for (int q = 0; q < 4; ++q)
            pf[k2 * 4 + q] = *reinterpret_cast<const float4*>(Pb + rbase + q * 4);
    }

    for (int c = 0; c < NCHUNK; ++c) {
        // ---- stage: sigmoid + LDS write (single buffer: prior chunk fully
        //      consumed by this wave already; in-order DS makes this safe)
        #pragma unroll
        for (int k2 = 0; k2 < 4; ++k2) {
            const int r = lane + 64 * k2;
            #pragma unroll
            for (int q = 0; q < 4; ++q) {
                const float4 v = pf[k2 * 4 + q];
                const float xs[4] = {v.x, v.y, v.z, v.w};
                #pragma unroll
                for (int j = 0; j < 4; ++j) {
                    float x = fminf(2.0f, fmaxf(-2.0f, xs[j]));
                    lds[r * XT_LD + 4 * q + j] = 1.0f / (1.0f + __expf(-4.0f * x));
                }
            }
        }
        // ---- issue next chunk's global loads; they complete under the scan
        if (c + 1 < NCHUNK) {
            #pragma unroll
            for (int k2 = 0; k2 < 4; ++k2) {
                const size_t rbase = (size_t)(lane + 64 * k2) * ((size_t)NBATCH * TT);
                #pragma unroll
                for (int q = 0; q < 4; ++q)
                    pf[k2 * 4 + q] = *reinterpret_cast<const float4*>(
                        Pb + rbase + (c + 1) * TC + q * 4);
            }
        }
        // ---- scan TC steps: 8 gathers, 4 updates, 4 state writes. No barriers.
        const float* pa[4]; const float* pb[4];
        #pragma unroll
        for (int k = 0; k < 4; ++k) { pa[k] = pa0[k]; pb[k] = pb0[k]; }

        #pragma unroll
        for (int t = 0; t < TC; ++t) {
            float av[4], bv[4];
            // all reads before any state write => step reads pre-step values
            #pragma unroll
            for (int k = 0; k < 4; ++k) { av[k] = *pa[k]; bv[k] = *pb[k]; }
            #pragma unroll
            for (int k = 0; k < 4; ++k) {
                const float a  = av[k];
                const float bb = bv[k];
                const float ns = a + bb - 2.0f * a * bb;
                sv[k] = ns;
                lds[ST_BASE + lane + 64 * k] = ns;
                pa[k] += inca[k];
                pb[k] += incb[k];
            }
        }
    }

    #pragma unroll
    for (int k = 0; k < 4; ++k)
        out[(size_t)b * N_REG + lane + 64 * k] = sv[k];
}

extern "C" void kernel_launch(void* const* d_in, const int* in_sizes, int n_in,
                              void* d_out, int out_size, void* d_ws, size_t ws_size,
                              hipStream_t stream) {
    const float* P   = (const float*)d_in[0];
    const int*   wa  = (const int*)d_in[1];
    const int*   wb  = (const int*)d_in[2];
    float*       out = (float*)d_out;
    circuit_scan<<<NBATCH, 64, 0, stream>>>(P, wa, wb, out);
}